// Round 10
// baseline (195.427 us; speedup 1.0000x reference)
//
#include <hip/hip_runtime.h>
#include <string.h>

// ---------------------------------------------------------------------------
// BaseAttention: hs[B,S,H] @ w_qkv^T -> q,k,v -> MHA(mask) -> @ w_out^T
// B=2 S=2048 H=1024 NH=16 HD=64  SCALE=1/8
// R21 DIAGNOSTIC: flash kk-split into 2 dispatches (kbase 0 / 1024), each
// with the FULL 512-block grid (2 blocks/CU density preserved). Purpose:
// flash (~57us) has owned every top-5 counter slot for 9 rounds; the
// ~130us non-flash majority has NEVER produced a counter row. Halved flash
// (~30us/dispatch) drops below the gemms -> gemm_qkv (and maybe gemm_out)
// surface with MfmaUtil/VALU/occupancy/FETCH. Accepted cost ~+4-6us.
// Exact combine (fixed exp2 shift): d1 writes unnormalized O (f16, numerics
// validated R14/R15) + l to dead hs_c/wqkv_c; d2 folds partial into its
// epilogue. Gemms/convert byte-identical to R20.
// Ledger: R19 BK=64 twin-buf -7.8us WIN; R20 XCD-swizzle + BK=128 both
// NULL (qkv not staging-locality-bound; out not barrier-bound).
// ---------------------------------------------------------------------------

typedef __bf16    bf16x8 __attribute__((ext_vector_type(8)));
typedef _Float16  f16x4  __attribute__((ext_vector_type(4)));
typedef _Float16  f16x2  __attribute__((ext_vector_type(2)));
typedef float     f32x4  __attribute__((ext_vector_type(4)));

#define NTOK   4096   // B*S
#define HDIM   1024
#define SEQ    2048
#define NHEAD  16
#define F2SHIFT 4.0f          // exp2-domain shift
#define QSCALE  0.18033688f   // 0.125 * log2(e)
#define LSTRIDE 68            // LDS row stride in halfwords (34 dwords = bank floor)
#define KHALF  1024

__device__ __forceinline__ float bf2f(unsigned short u) {
    union { unsigned int i; float f; } x;
    x.i = ((unsigned int)u) << 16;
    return x.f;
}
__device__ __forceinline__ unsigned short f2bf(float f) {
    union { __bf16 h; unsigned short u; } x;
    x.h = (__bf16)f;   // v_cvt RNE
    return x.u;
}
__device__ __forceinline__ unsigned short f2h(float f) {
    union { _Float16 h; unsigned short u; } x;
    x.h = (_Float16)f; // v_cvt_f16_f32 RNE
    return x.u;
}
__device__ __forceinline__ float h2f(unsigned short u) {
    union { unsigned short u; _Float16 h; } x;
    x.u = u;
    return (float)x.h;
}
__device__ __forceinline__ f16x2 pkrtz(float a, float b) {
    union { __fp16 __attribute__((ext_vector_type(2))) i; f16x2 o; } x;
    x.i = __builtin_amdgcn_cvt_pkrtz(a, b);
    return x.o;
}

// wave-level dtype self-detection (P(miss) ~ 0.55^64)
__device__ __forceinline__ int detect_f32(const unsigned short* hs) {
    unsigned int idx = (threadIdx.x & 63) * 4096u;
    float f = bf2f(hs[idx]);
    return __any(!(fabsf(f) < 1e4f));
}

typedef const __attribute__((address_space(1))) unsigned int* gptr_u32;
typedef __attribute__((address_space(3))) unsigned int* lptr_u32;

__device__ __forceinline__ void async16(const unsigned short* g, unsigned short* l) {
    __builtin_amdgcn_global_load_lds((gptr_u32)g, (lptr_u32)l, 16, 0, 0);
}

// --------------------------- canonicalize to bf16 (f32 inputs only) --------
__global__ void convert3_kernel(const void* __restrict__ s0, const void* __restrict__ s1,
                                const void* __restrict__ s2, unsigned short* __restrict__ dst) {
    const int isf32 = detect_f32((const unsigned short*)s0);
    if (!isf32) return;   // bf16 inputs: gemms read the raw pointers directly
    int g = blockIdx.x * blockDim.x + threadIdx.x;
    const int stride = gridDim.x * blockDim.x;
    for (; g < 1048576; g += stride) {
        int i = g * 8;
        const void* src; int off;
        if (i < 4194304)      { src = s0; off = i; }
        else if (i < 7340032) { src = s1; off = i - 4194304; }
        else                  { src = s2; off = i - 7340032; }
        const float* s = (const float*)src + off;
        unsigned short o[8];
#pragma unroll
        for (int j = 0; j < 8; j++) o[j] = f2bf(s[j]);
        *(uint4*)(dst + i) = *(const uint4*)o;
    }
}

// --------------------------- MFMA GEMM 0: QKV = hs @ w_qkv^T ---------------
// 128x128 tile, BK=64 twin buffers, XCD-swizzled 1D grid.
// Scatters q/k [B,NH,S,HD] bf16 (q *= QSCALE), v TRANSPOSED [B,NH,HD,S] f16.
__global__ __launch_bounds__(256) void gemm_qkv(
    const unsigned short* __restrict__ Xc, const unsigned short* __restrict__ Wc,
    const unsigned short* __restrict__ Xraw, const unsigned short* __restrict__ Wraw,
    unsigned short* __restrict__ q_out, unsigned short* __restrict__ k_out,
    unsigned short* __restrict__ v_out) {
    const int K = 1024;
    __shared__ __align__(16) unsigned short Xs0[128 * 32];
    __shared__ __align__(16) unsigned short Xs1[128 * 32];
    __shared__ __align__(16) unsigned short Ws0[128 * 32];
    __shared__ __align__(16) unsigned short Ws1[128 * 32];

    const int isf32 = detect_f32(Xraw);
    const unsigned short* X = isf32 ? Xc : Xraw;
    const unsigned short* W = isf32 ? Wc : Wraw;

    const int t = threadIdx.x;
    const int w = t >> 6, lane = t & 63, quad = lane >> 4, lr = lane & 15;
    const int wrow = (w >> 1) * 64, wcol = (w & 1) * 64;

    const int hid = blockIdx.x;
    const int xcd = hid & 7, r = hid >> 3;
    const int by = xcd * 4 + r / 24;   // 0..31  (X/m panel)
    const int bx = r % 24;             // 0..23  (W/n panel)
    const int m0 = by * 128, n0 = bx * 128;
    const bool vblk = (n0 >= 2048);

    f32x4 acc[4][4];
#pragma unroll
    for (int mi = 0; mi < 4; mi++)
#pragma unroll
        for (int ni = 0; ni < 4; ni++) acc[mi][ni] = (f32x4){0.f, 0.f, 0.f, 0.f};

    const int srow = w * 32 + (lane >> 2);
    const int scol = (lane & 3) * 8;
    const unsigned short* xg = X + (size_t)(m0 + srow) * K + scol;
    const unsigned short* wg = W + (size_t)(n0 + srow) * K + scol;
    unsigned short* xl0 = &Xs0[w * 1024];
    unsigned short* xl1 = &Xs1[w * 1024];
    unsigned short* wl0 = &Ws0[w * 1024];
    unsigned short* wl1 = &Ws1[w * 1024];

    for (int k0 = 0; k0 < K; k0 += 64) {
        __syncthreads();
        async16(xg + k0, xl0);
        async16(xg + k0 + 16 * K, xl0 + 512);
        async16(xg + k0 + 32, xl1);
        async16(xg + k0 + 32 + 16 * K, xl1 + 512);
        async16(wg + k0, wl0);
        async16(wg + k0 + 16 * K, wl0 + 512);
        async16(wg + k0 + 32, wl1);
        async16(wg + k0 + 32 + 16 * K, wl1 + 512);
        __syncthreads();
#pragma unroll
        for (int h = 0; h < 2; h++) {
            const unsigned short* Xh = h ? Xs1 : Xs0;
            const unsigned short* Wh = h ? Ws1 : Ws0;
            bf16x8 af[4], bfr[4];
#pragma unroll
            for (int mi = 0; mi < 4; mi++)
                af[mi] = *(const bf16x8*)&Xh[(wrow + mi * 16 + lr) * 32 + quad * 8];
#pragma unroll
            for (int ni = 0; ni < 4; ni++)
                bfr[ni] = *(const bf16x8*)&Wh[(wcol + ni * 16 + lr) * 32 + quad * 8];
            if (!vblk) {
#pragma unroll
                for (int mi = 0; mi < 4; mi++)
#pragma unroll
                    for (int ni = 0; ni < 4; ni++)
                        acc[mi][ni] = __builtin_amdgcn_mfma_f32_16x16x32_bf16(af[mi], bfr[ni], acc[mi][ni], 0, 0, 0);
            } else {
#pragma unroll
                for (int mi = 0; mi < 4; mi++)
#pragma unroll
                    for (int ni = 0; ni < 4; ni++)
                        acc[mi][ni] = __builtin_amdgcn_mfma_f32_16x16x32_bf16(bfr[ni], af[mi], acc[mi][ni], 0, 0, 0);
            }
        }
    }

    if (!vblk) {
#pragma unroll
        for (int mi = 0; mi < 4; mi++)
#pragma unroll
            for (int ni = 0; ni < 4; ni++)
#pragma unroll
                for (int rr = 0; rr < 4; rr++) {
                    int mrow = m0 + wrow + mi * 16 + quad * 4 + rr;  // token
                    int j = n0 + wcol + ni * 16 + lr;                // [0,2048)
                    float val = acc[mi][ni][rr];
                    int which = j >> 10, rem = j & 1023;
                    int nh = rem >> 6, hd = rem & 63;
                    int b = mrow >> 11, s = mrow & 2047;
                    size_t dst = ((size_t)(b * NHEAD + nh) * SEQ + s) * 64 + hd;
                    if (which == 0) q_out[dst] = f2bf(val * QSCALE);
                    else            k_out[dst] = f2bf(val);
                }
    } else {
#pragma unroll
        for (int mi = 0; mi < 4; mi++)
#pragma unroll
            for (int ni = 0; ni < 4; ni++)
#pragma unroll
                for (int rr = 0; rr < 4; rr++) {
                    int n = n0 + wcol + ni * 16 + quad * 4 + rr;     // channel
                    int m = m0 + wrow + mi * 16 + lr;                // token
                    float val = acc[mi][ni][rr];
                    int rem = n & 1023;
                    int nh = rem >> 6, hd = rem & 63;
                    int b = m >> 11, s = m & 2047;
                    size_t dst = ((size_t)(b * NHEAD + nh) * 64 + hd) * SEQ + s;  // V^T f16
                    v_out[dst] = f2h(val);
                }
    }
}

// --------------------------- MFMA GEMM 1: out = ao @ w_out^T ---------------
// BK=128 via quad 32-wide buffers.
__global__ __launch_bounds__(256) void gemm_out(
    const unsigned short* __restrict__ X, const unsigned short* __restrict__ Wc,
    const unsigned short* __restrict__ Wraw,
    void* __restrict__ d_out, const unsigned short* __restrict__ hs_raw) {
    const int K = 1024, N = 1024;
    __shared__ __align__(16) unsigned short Xs0[64 * 32];
    __shared__ __align__(16) unsigned short Xs1[64 * 32];
    __shared__ __align__(16) unsigned short Xs2[64 * 32];
    __shared__ __align__(16) unsigned short Xs3[64 * 32];
    __shared__ __align__(16) unsigned short Ws0[128 * 32];
    __shared__ __align__(16) unsigned short Ws1[128 * 32];
    __shared__ __align__(16) unsigned short Ws2[128 * 32];
    __shared__ __align__(16) unsigned short Ws3[128 * 32];

    const int isf32 = detect_f32(hs_raw);
    const unsigned short* W = isf32 ? Wc : Wraw;

    const int t = threadIdx.x;
    const int w = t >> 6, lane = t & 63, quad = lane >> 4, lr = lane & 15;
    const int wrow = (w >> 1) * 32, wcol = (w & 1) * 64;
    const int m0 = blockIdx.y * 64, n0 = blockIdx.x * 128;

    f32x4 acc[2][4];
#pragma unroll
    for (int mi = 0; mi < 2; mi++)
#pragma unroll
        for (int ni = 0; ni < 4; ni++) acc[mi][ni] = (f32x4){0.f, 0.f, 0.f, 0.f};

    const int sxrow = w * 16 + (lane >> 2);
    const int swrow = w * 32 + (lane >> 2);
    const int scol = (lane & 3) * 8;
    const unsigned short* xg = X + (size_t)(m0 + sxrow) * K + scol;
    const unsigned short* wg = W + (size_t)(n0 + swrow) * K + scol;
    unsigned short* xl[4] = { &Xs0[w * 512], &Xs1[w * 512], &Xs2[w * 512], &Xs3[w * 512] };
    unsigned short* wl[4] = { &Ws0[w * 1024], &Ws1[w * 1024], &Ws2[w * 1024], &Ws3[w * 1024] };

    for (int k0 = 0; k0 < K; k0 += 128) {
        __syncthreads();
#pragma unroll
        for (int j = 0; j < 4; j++) {
            async16(xg + k0 + j * 32, xl[j]);
            async16(wg + k0 + j * 32, wl[j]);
            async16(wg + k0 + j * 32 + 16 * K, wl[j] + 512);
        }
        __syncthreads();
#pragma unroll
        for (int h = 0; h < 4; h++) {
            const unsigned short* Xh = (h == 0) ? Xs0 : (h == 1) ? Xs1 : (h == 2) ? Xs2 : Xs3;
            const unsigned short* Wh = (h == 0) ? Ws0 : (h == 1) ? Ws1 : (h == 2) ? Ws2 : Ws3;
            bf16x8 af[2], bfr[4];
#pragma unroll
            for (int mi = 0; mi < 2; mi++)
                af[mi] = *(const bf16x8*)&Xh[(wrow + mi * 16 + lr) * 32 + quad * 8];
#pragma unroll
            for (int ni = 0; ni < 4; ni++)
                bfr[ni] = *(const bf16x8*)&Wh[(wcol + ni * 16 + lr) * 32 + quad * 8];
#pragma unroll
            for (int mi = 0; mi < 2; mi++)
#pragma unroll
                for (int ni = 0; ni < 4; ni++)
                    acc[mi][ni] = __builtin_amdgcn_mfma_f32_16x16x32_bf16(af[mi], bfr[ni], acc[mi][ni], 0, 0, 0);
        }
    }

#pragma unroll
    for (int mi = 0; mi < 2; mi++)
#pragma unroll
        for (int ni = 0; ni < 4; ni++)
#pragma unroll
            for (int rr = 0; rr < 4; rr++) {
                int mrow = m0 + wrow + mi * 16 + quad * 4 + rr;
                int j = n0 + wcol + ni * 16 + lr;
                float val = acc[mi][ni][rr];
                size_t dst = (size_t)mrow * N + j;
                if (isf32) ((float*)d_out)[dst] = val;
                else ((unsigned short*)d_out)[dst] = f2bf(val);
            }
}

// --------------------------- MFMA flash attention v13 (kk-split) -----------
// v12 per-tile structure, kk range [kbase, kbase+1024) per dispatch.
// Dispatch kbase=0: write unnormalized O (f16, same scatter as ao) + l.
// Dispatch kbase=1024: compute its half, fold partial in epilogue, write ao.
// Exact combine (fixed exp2 shift): O=(O0+O1)/(l0+l1). grid (32,16), 4 waves.
__global__ __launch_bounds__(256, 2) void flash_attn_v13(
    const unsigned short* __restrict__ q, const unsigned short* __restrict__ k,
    const unsigned short* __restrict__ vt, const int* __restrict__ mask,
    unsigned short* __restrict__ attn_out,
    unsigned short* __restrict__ opart, float* __restrict__ lpart,
    const int kbase) {
    __shared__ __align__(16) unsigned short Ks[128 * LSTRIDE];   // bf16, kk rows
    __shared__ __align__(16) unsigned short Vt0[64 * LSTRIDE];   // f16, d rows
    __shared__ __align__(16) unsigned short Vt1[64 * LSTRIDE];   // f16, d rows
    __shared__ __align__(16) float Msk[136];

    const int t = threadIdx.x;
    const int w = t >> 6, lane = t & 63, quad = lane >> 4, lr = lane & 15;
    const int bh = blockIdx.x, b = bh >> 4, h = bh & 15;
    const int q0 = blockIdx.y * 128;

    const unsigned short* qb = q + (size_t)bh * SEQ * 64;
    const unsigned short* kb = k + (size_t)bh * SEQ * 64;
    const unsigned short* vtb = vt + (size_t)bh * 64 * SEQ;
    const int* mb = mask + b * SEQ;

    // Q B-frags (x32 layout: B[n=lr][k=quad*8+j]), 2 q-groups x 2 hd-halves
    bf16x8 qf[2][2];
#pragma unroll
    for (int qg = 0; qg < 2; qg++) {
        const unsigned short* qrow = qb + (size_t)(q0 + w * 32 + qg * 16 + lr) * 64 + quad * 8;
        qf[qg][0] = *(const bf16x8*)qrow;
        qf[qg][1] = *(const bf16x8*)(qrow + 32);
    }

    f32x4 oacc[2][4];   // [qg][dt], O^T C-layout (d=dt*16+quad*4+rr, q=lr)
#pragma unroll
    for (int qg = 0; qg < 2; qg++)
#pragma unroll
        for (int dt = 0; dt < 4; dt++) oacc[qg][dt] = (f32x4){0.f, 0.f, 0.f, 0.f};
    float l_st[2] = {0.f, 0.f};

    const int sr = t >> 2;          // staging row 0..63
    const int sc = (t & 3) * 16;    // staging col group

    for (int kk0 = kbase; kk0 < kbase + KHALF; kk0 += 128) {
        const uint4* kp0 = (const uint4*)(kb + (size_t)(kk0 + sr) * 64 + sc);
        const uint4* kp1 = (const uint4*)(kb + (size_t)(kk0 + 64 + sr) * 64 + sc);
        const uint4* vp0 = (const uint4*)(vtb + (size_t)sr * SEQ + kk0 + sc);
        const uint4* vp1 = (const uint4*)(vtb + (size_t)sr * SEQ + kk0 + 64 + sc);
        uint4 k0a = kp0[0], k0b = kp0[1];
        uint4 k1a = kp1[0], k1b = kp1[1];
        uint4 v0a = vp0[0], v0b = vp0[1];
        uint4 v1a = vp1[0], v1b = vp1[1];
        float mval = 0.f;
        if (t < 128) mval = (mb[kk0 + t] == 0) ? -1e30f : -F2SHIFT;

        __syncthreads();
        *(uint4*)&Ks[sr * LSTRIDE + sc] = k0a;
        *(uint4*)&Ks[sr * LSTRIDE + sc + 8] = k0b;
        *(uint4*)&Ks[(64 + sr) * LSTRIDE + sc] = k1a;
        *(uint4*)&Ks[(64 + sr) * LSTRIDE + sc + 8] = k1b;
        *(uint4*)&Vt0[sr * LSTRIDE + sc] = v0a;
        *(uint4*)&Vt0[sr * LSTRIDE + sc + 8] = v0b;
        *(uint4*)&Vt1[sr * LSTRIDE + sc] = v1a;
        *(uint4*)&Vt1[sr * LSTRIDE + sc + 8] = v1b;
        if (t < 128) Msk[t] = mval;
        __syncthreads();

        __builtin_amdgcn_s_setprio(1);
#pragma unroll
        for (int mt = 0; mt < 8; mt++) {
            bf16x8 a1h0 = *(bf16x8*)&Ks[(mt * 16 + lr) * LSTRIDE + quad * 8];
            bf16x8 a1h1 = *(bf16x8*)&Ks[(mt * 16 + lr) * LSTRIDE + 32 + quad * 8];
            const unsigned short* vb_ = (mt < 4) ? Vt0 : Vt1;
            const int mcol = (mt & 3) * 16;
            f16x4 a2[4];
#pragma unroll
            for (int dt = 0; dt < 4; dt++)
                a2[dt] = *(const f16x4*)&vb_[(dt * 16 + lr) * LSTRIDE + mcol + quad * 4];
            float4 mv = *(const float4*)&Msk[mt * 16 + quad * 4];
            f32x4 zi = (f32x4){mv.x, mv.y, mv.z, mv.w};

#pragma unroll
            for (int qg = 0; qg < 2; qg++) {
                f32x4 z = __builtin_amdgcn_mfma_f32_16x16x32_bf16(a1h0, qf[qg][0], zi, 0, 0, 0);
                z = __builtin_amdgcn_mfma_f32_16x16x32_bf16(a1h1, qf[qg][1], z, 0, 0, 0);
                float p0 = __builtin_amdgcn_exp2f(z[0]);
                float p1 = __builtin_amdgcn_exp2f(z[1]);
                float p2 = __builtin_amdgcn_exp2f(z[2]);
                float p3 = __builtin_amdgcn_exp2f(z[3]);
                l_st[qg] += (p0 + p1) + (p2 + p3);
                f16x2 ab = pkrtz(p0, p1);
                f16x2 cd = pkrtz(p2, p3);
                f16x4 b2;
                b2[0] = ab[0]; b2[1] = ab[1]; b2[2] = cd[0]; b2[3] = cd[1];
#pragma unroll
                for (int dt = 0; dt < 4; dt++)
                    oacc[qg][dt] = __builtin_amdgcn_mfma_f32_16x16x16f16(a2[dt], b2, oacc[qg][dt], 0, 0, 0);
            }
        }
        __builtin_amdgcn_s_setprio(0);
    }

    // l: sum over quads (each quad held a disjoint kk subset)
    float lsum[2];
#pragma unroll
    for (int qg = 0; qg < 2; qg++) {
        float s = l_st[qg];
        s += __shfl_xor(s, 16);
        s += __shfl_xor(s, 32);
        lsum[qg] = s;
    }

    if (kbase == 0) {
        // dispatch 1: unnormalized O partial (f16) + l
#pragma unroll
        for (int qg = 0; qg < 2; qg++) {
            const int qrow = q0 + w * 32 + qg * 16 + lr;
            if (quad == 0) lpart[bh * 2048 + qrow] = lsum[qg];
            size_t tok = (size_t)(b * SEQ + qrow);
#pragma unroll
            for (int dt = 0; dt < 4; dt++)
#pragma unroll
                for (int rr = 0; rr < 4; rr++)
                    opart[tok * HDIM + h * 64 + dt * 16 + quad * 4 + rr] =
                        f2h(oacc[qg][dt][rr]);
        }
    } else {
        // dispatch 2: fold partial, normalize, write final bf16
#pragma unroll
        for (int qg = 0; qg < 2; qg++) {
            const int qrow = q0 + w * 32 + qg * 16 + lr;
            const float inv = 1.0f / (lsum[qg] + lpart[bh * 2048 + qrow]);
            size_t tok = (size_t)(b * SEQ + qrow);
#pragma unroll
            for (int dt = 0; dt < 4; dt++) {
                const unsigned short* op = &opart[tok * HDIM + h * 64 + dt * 16 + quad * 4];
#pragma unroll
                for (int rr = 0; rr < 4; rr++)
                    attn_out[tok * HDIM + h * 64 + dt * 16 + quad * 4 + rr] =
                        f2bf((oacc[qg][dt][rr] + h2f(op[rr])) * inv);
            }
        }
    }
}

// ---------------------------------------------------------------------------
extern "C" void kernel_launch(void* const* d_in, const int* in_sizes, int n_in,
                              void* d_out, int out_size, void* d_ws, size_t ws_size,
                              hipStream_t stream) {
    const void* hs_raw = d_in[0];
    const int* mask = (const int*)d_in[1];
    const void* wqkv_raw = d_in[2];
    const void* wout_raw = d_in[3];

    char* wsb = (char*)d_ws;
    unsigned short* hs_c = (unsigned short*)(wsb + 256);
    unsigned short* wqkv_c = hs_c + 4194304;     // 2*2048*1024
    unsigned short* wout_c = wqkv_c + 3145728;   // 3072*1024
    unsigned short* qw = wout_c + 1048576;       // 1024*1024
    unsigned short* kw = qw + 4194304;
    unsigned short* vtw = kw + 4194304;          // V^T [B,NH,HD,S] f16
    unsigned short* ao = vtw + 4194304;          // attn_out [4096,1024] bf16

    // overlays for flash partials (dead after gemm_qkv, stream-ordered):
    unsigned short* opart = hs_c;                // unnormalized O half-0, f16 8MB
    float* lpart = (float*)wqkv_c;               // l half-0, f32 256KB

    convert3_kernel<<<1024, 256, 0, stream>>>(hs_raw, wqkv_raw, wout_raw, hs_c);

    gemm_qkv<<<768, 256, 0, stream>>>(hs_c, wqkv_c,
                                      (const unsigned short*)hs_raw,
                                      (const unsigned short*)wqkv_raw,
                                      qw, kw, vtw);
    flash_attn_v13<<<dim3(32, 16), 256, 0, stream>>>(qw, kw, vtw, mask, ao, opart, lpart, 0);
    flash_attn_v13<<<dim3(32, 16), 256, 0, stream>>>(qw, kw, vtw, mask, ao, opart, lpart, 1024);
    gemm_out<<<dim3(8, 64), 256, 0, stream>>>(ao, wout_c,
                                              (const unsigned short*)wout_raw, d_out,
                                              (const unsigned short*)hs_raw);
}

// Round 11
// 191.999 us; speedup vs baseline: 1.0179x; 1.0179x over previous
//
#include <hip/hip_runtime.h>
#include <string.h>

// ---------------------------------------------------------------------------
// BaseAttention: hs[B,S,H] @ w_qkv^T -> q,k,v -> MHA(mask) -> @ w_out^T
// B=2 S=2048 H=1024 NH=16 HD=64  SCALE=1/8
// R22: first gemm_qkv round WITH counters (R21 diagnostic: 53.9us, MFMA 18.6%,
// VALU 11%, HBM 19%, 3.1M bank conflicts, occ 15.8% -> ~50% pure stall).
// Root cause in source: async16 issued after barrier A, drained at barrier B
// with ZERO work between -> full L2 latency exposed 16x/block (m233's
// 2-phase stall regime). Fix = T3/T4 minimum recipe: twin half-buffers
// become a DOUBLE buffer; per BK=32 step: barrier -> STAGE(other, k+32) ->
// compute(this). Drain lands after a full compute phase. One barrier/step,
// LDS still 32KB -> 3 blocks/CU (768=256x3, no tail). + T5 setprio around
// MFMA (proven +7% on CU-sharing blocks, R17).
// T2 swizzle deliberately NOT applied (regime gate: null at 2-phase, m252).
// Flash v13 kk-split diagnostic RETAINED this round for counter verify;
// revert next round (banked: R20 merged = 187.1us).
// Predicted: qkv 53.9 -> ~42-47, MfmaUtil -> ~26; total -> ~185-189.
// ---------------------------------------------------------------------------

typedef __bf16    bf16x8 __attribute__((ext_vector_type(8)));
typedef _Float16  f16x4  __attribute__((ext_vector_type(4)));
typedef _Float16  f16x2  __attribute__((ext_vector_type(2)));
typedef float     f32x4  __attribute__((ext_vector_type(4)));

#define NTOK   4096   // B*S
#define HDIM   1024
#define SEQ    2048
#define NHEAD  16
#define F2SHIFT 4.0f          // exp2-domain shift
#define QSCALE  0.18033688f   // 0.125 * log2(e)
#define LSTRIDE 68            // LDS row stride in halfwords (34 dwords = bank floor)
#define KHALF  1024

__device__ __forceinline__ float bf2f(unsigned short u) {
    union { unsigned int i; float f; } x;
    x.i = ((unsigned int)u) << 16;
    return x.f;
}
__device__ __forceinline__ unsigned short f2bf(float f) {
    union { __bf16 h; unsigned short u; } x;
    x.h = (__bf16)f;   // v_cvt RNE
    return x.u;
}
__device__ __forceinline__ unsigned short f2h(float f) {
    union { _Float16 h; unsigned short u; } x;
    x.h = (_Float16)f; // v_cvt_f16_f32 RNE
    return x.u;
}
__device__ __forceinline__ float h2f(unsigned short u) {
    union { unsigned short u; _Float16 h; } x;
    x.u = u;
    return (float)x.h;
}
__device__ __forceinline__ f16x2 pkrtz(float a, float b) {
    union { __fp16 __attribute__((ext_vector_type(2))) i; f16x2 o; } x;
    x.i = __builtin_amdgcn_cvt_pkrtz(a, b);
    return x.o;
}

// wave-level dtype self-detection (P(miss) ~ 0.55^64)
__device__ __forceinline__ int detect_f32(const unsigned short* hs) {
    unsigned int idx = (threadIdx.x & 63) * 4096u;
    float f = bf2f(hs[idx]);
    return __any(!(fabsf(f) < 1e4f));
}

typedef const __attribute__((address_space(1))) unsigned int* gptr_u32;
typedef __attribute__((address_space(3))) unsigned int* lptr_u32;

__device__ __forceinline__ void async16(const unsigned short* g, unsigned short* l) {
    __builtin_amdgcn_global_load_lds((gptr_u32)g, (lptr_u32)l, 16, 0, 0);
}

// --------------------------- canonicalize to bf16 (f32 inputs only) --------
__global__ void convert3_kernel(const void* __restrict__ s0, const void* __restrict__ s1,
                                const void* __restrict__ s2, unsigned short* __restrict__ dst) {
    const int isf32 = detect_f32((const unsigned short*)s0);
    if (!isf32) return;   // bf16 inputs: gemms read the raw pointers directly
    int g = blockIdx.x * blockDim.x + threadIdx.x;
    const int stride = gridDim.x * blockDim.x;
    for (; g < 1048576; g += stride) {
        int i = g * 8;
        const void* src; int off;
        if (i < 4194304)      { src = s0; off = i; }
        else if (i < 7340032) { src = s1; off = i - 4194304; }
        else                  { src = s2; off = i - 7340032; }
        const float* s = (const float*)src + off;
        unsigned short o[8];
#pragma unroll
        for (int j = 0; j < 8; j++) o[j] = f2bf(s[j]);
        *(uint4*)(dst + i) = *(const uint4*)o;
    }
}

// --------------------------- MFMA GEMM 0: QKV = hs @ w_qkv^T ---------------
// 128x128 tile, 4 waves (2x2), XCD-swizzled 1D grid. R22: double-buffered
// BK=32 pipeline — per step: barrier -> STAGE(next buf) -> compute(cur buf).
// Scatters q/k [B,NH,S,HD] bf16 (q *= QSCALE), v TRANSPOSED [B,NH,HD,S] f16.
__global__ __launch_bounds__(256) void gemm_qkv(
    const unsigned short* __restrict__ Xc, const unsigned short* __restrict__ Wc,
    const unsigned short* __restrict__ Xraw, const unsigned short* __restrict__ Wraw,
    unsigned short* __restrict__ q_out, unsigned short* __restrict__ k_out,
    unsigned short* __restrict__ v_out) {
    const int K = 1024;
    __shared__ __align__(16) unsigned short Xs0[128 * 32];
    __shared__ __align__(16) unsigned short Xs1[128 * 32];
    __shared__ __align__(16) unsigned short Ws0[128 * 32];
    __shared__ __align__(16) unsigned short Ws1[128 * 32];

    const int isf32 = detect_f32(Xraw);
    const unsigned short* X = isf32 ? Xc : Xraw;
    const unsigned short* W = isf32 ? Wc : Wraw;

    const int t = threadIdx.x;
    const int w = t >> 6, lane = t & 63, quad = lane >> 4, lr = lane & 15;
    const int wrow = (w >> 1) * 64, wcol = (w & 1) * 64;

    const int hid = blockIdx.x;
    const int xcd = hid & 7, r = hid >> 3;
    const int by = xcd * 4 + r / 24;   // 0..31  (X/m panel)
    const int bx = r % 24;             // 0..23  (W/n panel)
    const int m0 = by * 128, n0 = bx * 128;
    const bool vblk = (n0 >= 2048);

    f32x4 acc[4][4];
#pragma unroll
    for (int mi = 0; mi < 4; mi++)
#pragma unroll
        for (int ni = 0; ni < 4; ni++) acc[mi][ni] = (f32x4){0.f, 0.f, 0.f, 0.f};

    const int srow = w * 32 + (lane >> 2);
    const int scol = (lane & 3) * 8;
    const unsigned short* xg = X + (size_t)(m0 + srow) * K + scol;
    const unsigned short* wg = W + (size_t)(n0 + srow) * K + scol;
    unsigned short* xl0 = &Xs0[w * 1024];
    unsigned short* xl1 = &Xs1[w * 1024];
    unsigned short* wl0 = &Ws0[w * 1024];
    unsigned short* wl1 = &Ws1[w * 1024];

    // prologue: stage k=0 into buffer 0
    async16(xg, xl0);
    async16(xg + 16 * K, xl0 + 512);
    async16(wg, wl0);
    async16(wg + 16 * K, wl0 + 512);

#define QKV_COMPUTE(Xh, Wh)                                                            \
    {                                                                                  \
        bf16x8 af[4], bfr[4];                                                          \
        _Pragma("unroll")                                                              \
        for (int mi = 0; mi < 4; mi++)                                                 \
            af[mi] = *(const bf16x8*)&Xh[(wrow + mi * 16 + lr) * 32 + quad * 8];       \
        _Pragma("unroll")                                                              \
        for (int ni = 0; ni < 4; ni++)                                                 \
            bfr[ni] = *(const bf16x8*)&Wh[(wcol + ni * 16 + lr) * 32 + quad * 8];      \
        __builtin_amdgcn_s_setprio(1);                                                 \
        if (!vblk) {                                                                   \
            _Pragma("unroll")                                                          \
            for (int mi = 0; mi < 4; mi++)                                             \
                _Pragma("unroll")                                                      \
                for (int ni = 0; ni < 4; ni++)                                         \
                    acc[mi][ni] = __builtin_amdgcn_mfma_f32_16x16x32_bf16(             \
                        af[mi], bfr[ni], acc[mi][ni], 0, 0, 0);                        \
        } else {                                                                       \
            _Pragma("unroll")                                                          \
            for (int mi = 0; mi < 4; mi++)                                             \
                _Pragma("unroll")                                                      \
                for (int ni = 0; ni < 4; ni++)                                         \
                    acc[mi][ni] = __builtin_amdgcn_mfma_f32_16x16x32_bf16(             \
                        bfr[ni], af[mi], acc[mi][ni], 0, 0, 0);                        \
        }                                                                              \
        __builtin_amdgcn_s_setprio(0);                                                 \
    }

    for (int k0 = 0; k0 < K; k0 += 64) {
        // phase 0: stage k0+32 into buf1, compute buf0 (k0)
        __syncthreads();   // drains this wave's buf0 loads (issued a full phase ago)
        async16(xg + k0 + 32, xl1);
        async16(xg + k0 + 32 + 16 * K, xl1 + 512);
        async16(wg + k0 + 32, wl1);
        async16(wg + k0 + 32 + 16 * K, wl1 + 512);
        QKV_COMPUTE(Xs0, Ws0);

        // phase 1: stage k0+64 into buf0, compute buf1 (k0+32)
        __syncthreads();
        if (k0 + 64 < K) {
            async16(xg + k0 + 64, xl0);
            async16(xg + k0 + 64 + 16 * K, xl0 + 512);
            async16(wg + k0 + 64, wl0);
            async16(wg + k0 + 64 + 16 * K, wl0 + 512);
        }
        QKV_COMPUTE(Xs1, Ws1);
    }
#undef QKV_COMPUTE

    if (!vblk) {
#pragma unroll
        for (int mi = 0; mi < 4; mi++)
#pragma unroll
            for (int ni = 0; ni < 4; ni++)
#pragma unroll
                for (int rr = 0; rr < 4; rr++) {
                    int mrow = m0 + wrow + mi * 16 + quad * 4 + rr;  // token
                    int j = n0 + wcol + ni * 16 + lr;                // [0,2048)
                    float val = acc[mi][ni][rr];
                    int which = j >> 10, rem = j & 1023;
                    int nh = rem >> 6, hd = rem & 63;
                    int b = mrow >> 11, s = mrow & 2047;
                    size_t dst = ((size_t)(b * NHEAD + nh) * SEQ + s) * 64 + hd;
                    if (which == 0) q_out[dst] = f2bf(val * QSCALE);
                    else            k_out[dst] = f2bf(val);
                }
    } else {
#pragma unroll
        for (int mi = 0; mi < 4; mi++)
#pragma unroll
            for (int ni = 0; ni < 4; ni++)
#pragma unroll
                for (int rr = 0; rr < 4; rr++) {
                    int n = n0 + wcol + ni * 16 + quad * 4 + rr;     // channel
                    int m = m0 + wrow + mi * 16 + lr;                // token
                    float val = acc[mi][ni][rr];
                    int rem = n & 1023;
                    int nh = rem >> 6, hd = rem & 63;
                    int b = m >> 11, s = m & 2047;
                    size_t dst = ((size_t)(b * NHEAD + nh) * 64 + hd) * SEQ + s;  // V^T f16
                    v_out[dst] = f2h(val);
                }
    }
}

// --------------------------- MFMA GEMM 1: out = ao @ w_out^T ---------------
// BK=128 via quad 32-wide buffers. Byte-identical to R21 (attribution guard).
__global__ __launch_bounds__(256) void gemm_out(
    const unsigned short* __restrict__ X, const unsigned short* __restrict__ Wc,
    const unsigned short* __restrict__ Wraw,
    void* __restrict__ d_out, const unsigned short* __restrict__ hs_raw) {
    const int K = 1024, N = 1024;
    __shared__ __align__(16) unsigned short Xs0[64 * 32];
    __shared__ __align__(16) unsigned short Xs1[64 * 32];
    __shared__ __align__(16) unsigned short Xs2[64 * 32];
    __shared__ __align__(16) unsigned short Xs3[64 * 32];
    __shared__ __align__(16) unsigned short Ws0[128 * 32];
    __shared__ __align__(16) unsigned short Ws1[128 * 32];
    __shared__ __align__(16) unsigned short Ws2[128 * 32];
    __shared__ __align__(16) unsigned short Ws3[128 * 32];

    const int isf32 = detect_f32(hs_raw);
    const unsigned short* W = isf32 ? Wc : Wraw;

    const int t = threadIdx.x;
    const int w = t >> 6, lane = t & 63, quad = lane >> 4, lr = lane & 15;
    const int wrow = (w >> 1) * 32, wcol = (w & 1) * 64;
    const int m0 = blockIdx.y * 64, n0 = blockIdx.x * 128;

    f32x4 acc[2][4];
#pragma unroll
    for (int mi = 0; mi < 2; mi++)
#pragma unroll
        for (int ni = 0; ni < 4; ni++) acc[mi][ni] = (f32x4){0.f, 0.f, 0.f, 0.f};

    const int sxrow = w * 16 + (lane >> 2);
    const int swrow = w * 32 + (lane >> 2);
    const int scol = (lane & 3) * 8;
    const unsigned short* xg = X + (size_t)(m0 + sxrow) * K + scol;
    const unsigned short* wg = W + (size_t)(n0 + swrow) * K + scol;
    unsigned short* xl[4] = { &Xs0[w * 512], &Xs1[w * 512], &Xs2[w * 512], &Xs3[w * 512] };
    unsigned short* wl[4] = { &Ws0[w * 1024], &Ws1[w * 1024], &Ws2[w * 1024], &Ws3[w * 1024] };

    for (int k0 = 0; k0 < K; k0 += 128) {
        __syncthreads();
#pragma unroll
        for (int j = 0; j < 4; j++) {
            async16(xg + k0 + j * 32, xl[j]);
            async16(wg + k0 + j * 32, wl[j]);
            async16(wg + k0 + j * 32 + 16 * K, wl[j] + 512);
        }
        __syncthreads();
#pragma unroll
        for (int h = 0; h < 4; h++) {
            const unsigned short* Xh = (h == 0) ? Xs0 : (h == 1) ? Xs1 : (h == 2) ? Xs2 : Xs3;
            const unsigned short* Wh = (h == 0) ? Ws0 : (h == 1) ? Ws1 : (h == 2) ? Ws2 : Ws3;
            bf16x8 af[2], bfr[4];
#pragma unroll
            for (int mi = 0; mi < 2; mi++)
                af[mi] = *(const bf16x8*)&Xh[(wrow + mi * 16 + lr) * 32 + quad * 8];
#pragma unroll
            for (int ni = 0; ni < 4; ni++)
                bfr[ni] = *(const bf16x8*)&Wh[(wcol + ni * 16 + lr) * 32 + quad * 8];
#pragma unroll
            for (int mi = 0; mi < 2; mi++)
#pragma unroll
                for (int ni = 0; ni < 4; ni++)
                    acc[mi][ni] = __builtin_amdgcn_mfma_f32_16x16x32_bf16(af[mi], bfr[ni], acc[mi][ni], 0, 0, 0);
        }
    }

#pragma unroll
    for (int mi = 0; mi < 2; mi++)
#pragma unroll
        for (int ni = 0; ni < 4; ni++)
#pragma unroll
            for (int rr = 0; rr < 4; rr++) {
                int mrow = m0 + wrow + mi * 16 + quad * 4 + rr;
                int j = n0 + wcol + ni * 16 + lr;
                float val = acc[mi][ni][rr];
                size_t dst = (size_t)mrow * N + j;
                if (isf32) ((float*)d_out)[dst] = val;
                else ((unsigned short*)d_out)[dst] = f2bf(val);
            }
}

// --------------------------- MFMA flash attention v13 (kk-split) -----------
// Diagnostic split retained this round (revert next). v12 per-tile structure,
// kk range [kbase, kbase+1024) per dispatch. Exact combine via fixed shift.
__global__ __launch_bounds__(256, 2) void flash_attn_v13(
    const unsigned short* __restrict__ q, const unsigned short* __restrict__ k,
    const unsigned short* __restrict__ vt, const int* __restrict__ mask,
    unsigned short* __restrict__ attn_out,
    unsigned short* __restrict__ opart, float* __restrict__ lpart,
    const int kbase) {
    __shared__ __align__(16) unsigned short Ks[128 * LSTRIDE];   // bf16, kk rows
    __shared__ __align__(16) unsigned short Vt0[64 * LSTRIDE];   // f16, d rows
    __shared__ __align__(16) unsigned short Vt1[64 * LSTRIDE];   // f16, d rows
    __shared__ __align__(16) float Msk[136];

    const int t = threadIdx.x;
    const int w = t >> 6, lane = t & 63, quad = lane >> 4, lr = lane & 15;
    const int bh = blockIdx.x, b = bh >> 4, h = bh & 15;
    const int q0 = blockIdx.y * 128;

    const unsigned short* qb = q + (size_t)bh * SEQ * 64;
    const unsigned short* kb = k + (size_t)bh * SEQ * 64;
    const unsigned short* vtb = vt + (size_t)bh * 64 * SEQ;
    const int* mb = mask + b * SEQ;

    // Q B-frags (x32 layout: B[n=lr][k=quad*8+j]), 2 q-groups x 2 hd-halves
    bf16x8 qf[2][2];
#pragma unroll
    for (int qg = 0; qg < 2; qg++) {
        const unsigned short* qrow = qb + (size_t)(q0 + w * 32 + qg * 16 + lr) * 64 + quad * 8;
        qf[qg][0] = *(const bf16x8*)qrow;
        qf[qg][1] = *(const bf16x8*)(qrow + 32);
    }

    f32x4 oacc[2][4];   // [qg][dt], O^T C-layout (d=dt*16+quad*4+rr, q=lr)
#pragma unroll
    for (int qg = 0; qg < 2; qg++)
#pragma unroll
        for (int dt = 0; dt < 4; dt++) oacc[qg][dt] = (f32x4){0.f, 0.f, 0.f, 0.f};
    float l_st[2] = {0.f, 0.f};

    const int sr = t >> 2;          // staging row 0..63
    const int sc = (t & 3) * 16;    // staging col group

    for (int kk0 = kbase; kk0 < kbase + KHALF; kk0 += 128) {
        const uint4* kp0 = (const uint4*)(kb + (size_t)(kk0 + sr) * 64 + sc);
        const uint4* kp1 = (const uint4*)(kb + (size_t)(kk0 + 64 + sr) * 64 + sc);
        const uint4* vp0 = (const uint4*)(vtb + (size_t)sr * SEQ + kk0 + sc);
        const uint4* vp1 = (const uint4*)(vtb + (size_t)sr * SEQ + kk0 + 64 + sc);
        uint4 k0a = kp0[0], k0b = kp0[1];
        uint4 k1a = kp1[0], k1b = kp1[1];
        uint4 v0a = vp0[0], v0b = vp0[1];
        uint4 v1a = vp1[0], v1b = vp1[1];
        float mval = 0.f;
        if (t < 128) mval = (mb[kk0 + t] == 0) ? -1e30f : -F2SHIFT;

        __syncthreads();
        *(uint4*)&Ks[sr * LSTRIDE + sc] = k0a;
        *(uint4*)&Ks[sr * LSTRIDE + sc + 8] = k0b;
        *(uint4*)&Ks[(64 + sr) * LSTRIDE + sc] = k1a;
        *(uint4*)&Ks[(64 + sr) * LSTRIDE + sc + 8] = k1b;
        *(uint4*)&Vt0[sr * LSTRIDE + sc] = v0a;
        *(uint4*)&Vt0[sr * LSTRIDE + sc + 8] = v0b;
        *(uint4*)&Vt1[sr * LSTRIDE + sc] = v1a;
        *(uint4*)&Vt1[sr * LSTRIDE + sc + 8] = v1b;
        if (t < 128) Msk[t] = mval;
        __syncthreads();

        __builtin_amdgcn_s_setprio(1);
#pragma unroll
        for (int mt = 0; mt < 8; mt++) {
            bf16x8 a1h0 = *(bf16x8*)&Ks[(mt * 16 + lr) * LSTRIDE + quad * 8];
            bf16x8 a1h1 = *(bf16x8*)&Ks[(mt * 16 + lr) * LSTRIDE + 32 + quad * 8];
            const unsigned short* vb_ = (mt < 4) ? Vt0 : Vt1;
            const int mcol = (mt & 3) * 16;
            f16x4 a2[4];
#pragma unroll
            for (int dt = 0; dt < 4; dt++)
                a2[dt] = *(const f16x4*)&vb_[(dt * 16 + lr) * LSTRIDE + mcol + quad * 4];
            float4 mv = *(const float4*)&Msk[mt * 16 + quad * 4];
            f32x4 zi = (f32x4){mv.x, mv.y, mv.z, mv.w};

#pragma unroll
            for (int qg = 0; qg < 2; qg++) {
                f32x4 z = __builtin_amdgcn_mfma_f32_16x16x32_bf16(a1h0, qf[qg][0], zi, 0, 0, 0);
                z = __builtin_amdgcn_mfma_f32_16x16x32_bf16(a1h1, qf[qg][1], z, 0, 0, 0);
                float p0 = __builtin_amdgcn_exp2f(z[0]);
                float p1 = __builtin_amdgcn_exp2f(z[1]);
                float p2 = __builtin_amdgcn_exp2f(z[2]);
                float p3 = __builtin_amdgcn_exp2f(z[3]);
                l_st[qg] += (p0 + p1) + (p2 + p3);
                f16x2 ab = pkrtz(p0, p1);
                f16x2 cd = pkrtz(p2, p3);
                f16x4 b2;
                b2[0] = ab[0]; b2[1] = ab[1]; b2[2] = cd[0]; b2[3] = cd[1];
#pragma unroll
                for (int dt = 0; dt < 4; dt++)
                    oacc[qg][dt] = __builtin_amdgcn_mfma_f32_16x16x16f16(a2[dt], b2, oacc[qg][dt], 0, 0, 0);
            }
        }
        __builtin_amdgcn_s_setprio(0);
    }

    // l: sum over quads (each quad held a disjoint kk subset)
    float lsum[2];
#pragma unroll
    for (int qg = 0; qg < 2; qg++) {
        float s = l_st[qg];
        s += __shfl_xor(s, 16);
        s += __shfl_xor(s, 32);
        lsum[qg] = s;
    }

    if (kbase == 0) {
        // dispatch 1: unnormalized O partial (f16) + l
#pragma unroll
        for (int qg = 0; qg < 2; qg++) {
            const int qrow = q0 + w * 32 + qg * 16 + lr;
            if (quad == 0) lpart[bh * 2048 + qrow] = lsum[qg];
            size_t tok = (size_t)(b * SEQ + qrow);
#pragma unroll
            for (int dt = 0; dt < 4; dt++)
#pragma unroll
                for (int rr = 0; rr < 4; rr++)
                    opart[tok * HDIM + h * 64 + dt * 16 + quad * 4 + rr] =
                        f2h(oacc[qg][dt][rr]);
        }
    } else {
        // dispatch 2: fold partial, normalize, write final bf16
#pragma unroll
        for (int qg = 0; qg < 2; qg++) {
            const int qrow = q0 + w * 32 + qg * 16 + lr;
            const float inv = 1.0f / (lsum[qg] + lpart[bh * 2048 + qrow]);
            size_t tok = (size_t)(b * SEQ + qrow);
#pragma unroll
            for (int dt = 0; dt < 4; dt++) {
                const unsigned short* op = &opart[tok * HDIM + h * 64 + dt * 16 + quad * 4];
#pragma unroll
                for (int rr = 0; rr < 4; rr++)
                    attn_out[tok * HDIM + h * 64 + dt * 16 + quad * 4 + rr] =
                        f2bf((oacc[qg][dt][rr] + h2f(op[rr])) * inv);
            }
        }
    }
}

// ---------------------------------------------------------------------------
extern "C" void kernel_launch(void* const* d_in, const int* in_sizes, int n_in,
                              void* d_out, int out_size, void* d_ws, size_t ws_size,
                              hipStream_t stream) {
    const void* hs_raw = d_in[0];
    const int* mask = (const int*)d_in[1];
    const void* wqkv_raw = d_in[2];
    const void* wout_raw = d_in[3];

    char* wsb = (char*)d_ws;
    unsigned short* hs_c = (unsigned short*)(wsb + 256);
    unsigned short* wqkv_c = hs_c + 4194304;     // 2*2048*1024
    unsigned short* wout_c = wqkv_c + 3145728;   // 3072*1024
    unsigned short* qw = wout_c + 1048576;       // 1024*1024
    unsigned short* kw = qw + 4194304;
    unsigned short* vtw = kw + 4194304;          // V^T [B,NH,HD,S] f16
    unsigned short* ao = vtw + 4194304;          // attn_out [4096,1024] bf16

    // overlays for flash partials (dead after gemm_qkv, stream-ordered):
    unsigned short* opart = hs_c;                // unnormalized O half-0, f16 8MB
    float* lpart = (float*)wqkv_c;               // l half-0, f32 256KB

    convert3_kernel<<<1024, 256, 0, stream>>>(hs_raw, wqkv_raw, wout_raw, hs_c);

    gemm_qkv<<<768, 256, 0, stream>>>(hs_c, wqkv_c,
                                      (const unsigned short*)hs_raw,
                                      (const unsigned short*)wqkv_raw,
                                      qw, kw, vtw);
    flash_attn_v13<<<dim3(32, 16), 256, 0, stream>>>(qw, kw, vtw, mask, ao, opart, lpart, 0);
    flash_attn_v13<<<dim3(32, 16), 256, 0, stream>>>(qw, kw, vtw, mask, ao, opart, lpart, 1024);
    gemm_out<<<dim3(8, 64), 256, 0, stream>>>(ao, wout_c,
                                              (const unsigned short*)wout_raw, d_out,
                                              (const unsigned short*)hs_raw);
}

// Round 12
// 183.189 us; speedup vs baseline: 1.0668x; 1.0481x over previous
//
#include <hip/hip_runtime.h>
#include <string.h>

// ---------------------------------------------------------------------------
// BaseAttention: hs[B,S,H] @ w_qkv^T -> q,k,v -> MHA(mask) -> @ w_out^T
// B=2 S=2048 H=1024 NH=16 HD=64  SCALE=1/8
// R23: bank the owed items. (1) Revert flash kk-split diagnostic (-8.3us:
// job done, gemm_qkv counters captured R21/R22) -> flash v12 single
// dispatch, byte-identical R18-R20. (2) Port R22's double-buffer pipeline
// to gemm_out (mechanism 3-for-3: flash KVBLK, R19 twin-buf, R22 qkv
// pipeline +15.6%): twin BK=32 buffers, per phase barrier -> stage(next)
// -> setprio MFMA(cur). Replaces R20 burst-stage (exposed latency).
// gemm_qkv byte-identical R22 (45.5us, MfmaUtil 21.2, conflicts 3.1M).
// Ledger: qkv at 562 TF vs m97's 874 — gap is short-K amortization
// (32 K-steps vs 128) + scatter epilogue; tile rework = future big swing.
// Predicted: total 192.0 -> ~179-182; flash ~54-57 tops table again.
// ---------------------------------------------------------------------------

typedef __bf16    bf16x8 __attribute__((ext_vector_type(8)));
typedef _Float16  f16x4  __attribute__((ext_vector_type(4)));
typedef _Float16  f16x2  __attribute__((ext_vector_type(2)));
typedef float     f32x4  __attribute__((ext_vector_type(4)));

#define NTOK   4096   // B*S
#define HDIM   1024
#define SEQ    2048
#define NHEAD  16
#define F2SHIFT 4.0f          // exp2-domain shift
#define QSCALE  0.18033688f   // 0.125 * log2(e)
#define LSTRIDE 68            // LDS row stride in halfwords (34 dwords = bank floor)

__device__ __forceinline__ float bf2f(unsigned short u) {
    union { unsigned int i; float f; } x;
    x.i = ((unsigned int)u) << 16;
    return x.f;
}
__device__ __forceinline__ unsigned short f2bf(float f) {
    union { __bf16 h; unsigned short u; } x;
    x.h = (__bf16)f;   // v_cvt RNE
    return x.u;
}
__device__ __forceinline__ unsigned short f2h(float f) {
    union { _Float16 h; unsigned short u; } x;
    x.h = (_Float16)f; // v_cvt_f16_f32 RNE
    return x.u;
}
__device__ __forceinline__ f16x2 pkrtz(float a, float b) {
    union { __fp16 __attribute__((ext_vector_type(2))) i; f16x2 o; } x;
    x.i = __builtin_amdgcn_cvt_pkrtz(a, b);
    return x.o;
}

// wave-level dtype self-detection (P(miss) ~ 0.55^64)
__device__ __forceinline__ int detect_f32(const unsigned short* hs) {
    unsigned int idx = (threadIdx.x & 63) * 4096u;
    float f = bf2f(hs[idx]);
    return __any(!(fabsf(f) < 1e4f));
}

typedef const __attribute__((address_space(1))) unsigned int* gptr_u32;
typedef __attribute__((address_space(3))) unsigned int* lptr_u32;

__device__ __forceinline__ void async16(const unsigned short* g, unsigned short* l) {
    __builtin_amdgcn_global_load_lds((gptr_u32)g, (lptr_u32)l, 16, 0, 0);
}

// --------------------------- canonicalize to bf16 (f32 inputs only) --------
__global__ void convert3_kernel(const void* __restrict__ s0, const void* __restrict__ s1,
                                const void* __restrict__ s2, unsigned short* __restrict__ dst) {
    const int isf32 = detect_f32((const unsigned short*)s0);
    if (!isf32) return;   // bf16 inputs: gemms read the raw pointers directly
    int g = blockIdx.x * blockDim.x + threadIdx.x;
    const int stride = gridDim.x * blockDim.x;
    for (; g < 1048576; g += stride) {
        int i = g * 8;
        const void* src; int off;
        if (i < 4194304)      { src = s0; off = i; }
        else if (i < 7340032) { src = s1; off = i - 4194304; }
        else                  { src = s2; off = i - 7340032; }
        const float* s = (const float*)src + off;
        unsigned short o[8];
#pragma unroll
        for (int j = 0; j < 8; j++) o[j] = f2bf(s[j]);
        *(uint4*)(dst + i) = *(const uint4*)o;
    }
}

// --------------------------- MFMA GEMM 0: QKV = hs @ w_qkv^T ---------------
// 128x128 tile, 4 waves (2x2), XCD-swizzled 1D grid. Double-buffered BK=32
// pipeline — per step: barrier -> STAGE(next buf) -> compute(cur buf).
// BYTE-IDENTICAL to R22 (45.5us measured).
// Scatters q/k [B,NH,S,HD] bf16 (q *= QSCALE), v TRANSPOSED [B,NH,HD,S] f16.
__global__ __launch_bounds__(256) void gemm_qkv(
    const unsigned short* __restrict__ Xc, const unsigned short* __restrict__ Wc,
    const unsigned short* __restrict__ Xraw, const unsigned short* __restrict__ Wraw,
    unsigned short* __restrict__ q_out, unsigned short* __restrict__ k_out,
    unsigned short* __restrict__ v_out) {
    const int K = 1024;
    __shared__ __align__(16) unsigned short Xs0[128 * 32];
    __shared__ __align__(16) unsigned short Xs1[128 * 32];
    __shared__ __align__(16) unsigned short Ws0[128 * 32];
    __shared__ __align__(16) unsigned short Ws1[128 * 32];

    const int isf32 = detect_f32(Xraw);
    const unsigned short* X = isf32 ? Xc : Xraw;
    const unsigned short* W = isf32 ? Wc : Wraw;

    const int t = threadIdx.x;
    const int w = t >> 6, lane = t & 63, quad = lane >> 4, lr = lane & 15;
    const int wrow = (w >> 1) * 64, wcol = (w & 1) * 64;

    const int hid = blockIdx.x;
    const int xcd = hid & 7, r = hid >> 3;
    const int by = xcd * 4 + r / 24;   // 0..31  (X/m panel)
    const int bx = r % 24;             // 0..23  (W/n panel)
    const int m0 = by * 128, n0 = bx * 128;
    const bool vblk = (n0 >= 2048);

    f32x4 acc[4][4];
#pragma unroll
    for (int mi = 0; mi < 4; mi++)
#pragma unroll
        for (int ni = 0; ni < 4; ni++) acc[mi][ni] = (f32x4){0.f, 0.f, 0.f, 0.f};

    const int srow = w * 32 + (lane >> 2);
    const int scol = (lane & 3) * 8;
    const unsigned short* xg = X + (size_t)(m0 + srow) * K + scol;
    const unsigned short* wg = W + (size_t)(n0 + srow) * K + scol;
    unsigned short* xl0 = &Xs0[w * 1024];
    unsigned short* xl1 = &Xs1[w * 1024];
    unsigned short* wl0 = &Ws0[w * 1024];
    unsigned short* wl1 = &Ws1[w * 1024];

    // prologue: stage k=0 into buffer 0
    async16(xg, xl0);
    async16(xg + 16 * K, xl0 + 512);
    async16(wg, wl0);
    async16(wg + 16 * K, wl0 + 512);

#define QKV_COMPUTE(Xh, Wh)                                                            \
    {                                                                                  \
        bf16x8 af[4], bfr[4];                                                          \
        _Pragma("unroll")                                                              \
        for (int mi = 0; mi < 4; mi++)                                                 \
            af[mi] = *(const bf16x8*)&Xh[(wrow + mi * 16 + lr) * 32 + quad * 8];       \
        _Pragma("unroll")                                                              \
        for (int ni = 0; ni < 4; ni++)                                                 \
            bfr[ni] = *(const bf16x8*)&Wh[(wcol + ni * 16 + lr) * 32 + quad * 8];      \
        __builtin_amdgcn_s_setprio(1);                                                 \
        if (!vblk) {                                                                   \
            _Pragma("unroll")                                                          \
            for (int mi = 0; mi < 4; mi++)                                             \
                _Pragma("unroll")                                                      \
                for (int ni = 0; ni < 4; ni++)                                         \
                    acc[mi][ni] = __builtin_amdgcn_mfma_f32_16x16x32_bf16(             \
                        af[mi], bfr[ni], acc[mi][ni], 0, 0, 0);                        \
        } else {                                                                       \
            _Pragma("unroll")                                                          \
            for (int mi = 0; mi < 4; mi++)                                             \
                _Pragma("unroll")                                                      \
                for (int ni = 0; ni < 4; ni++)                                         \
                    acc[mi][ni] = __builtin_amdgcn_mfma_f32_16x16x32_bf16(             \
                        bfr[ni], af[mi], acc[mi][ni], 0, 0, 0);                        \
        }                                                                              \
        __builtin_amdgcn_s_setprio(0);                                                 \
    }

    for (int k0 = 0; k0 < K; k0 += 64) {
        // phase 0: stage k0+32 into buf1, compute buf0 (k0)
        __syncthreads();   // drains buf0 loads (issued a full compute phase ago)
        async16(xg + k0 + 32, xl1);
        async16(xg + k0 + 32 + 16 * K, xl1 + 512);
        async16(wg + k0 + 32, wl1);
        async16(wg + k0 + 32 + 16 * K, wl1 + 512);
        QKV_COMPUTE(Xs0, Ws0);

        // phase 1: stage k0+64 into buf0, compute buf1 (k0+32)
        __syncthreads();
        if (k0 + 64 < K) {
            async16(xg + k0 + 64, xl0);
            async16(xg + k0 + 64 + 16 * K, xl0 + 512);
            async16(wg + k0 + 64, wl0);
            async16(wg + k0 + 64 + 16 * K, wl0 + 512);
        }
        QKV_COMPUTE(Xs1, Ws1);
    }
#undef QKV_COMPUTE

    if (!vblk) {
#pragma unroll
        for (int mi = 0; mi < 4; mi++)
#pragma unroll
            for (int ni = 0; ni < 4; ni++)
#pragma unroll
                for (int rr = 0; rr < 4; rr++) {
                    int mrow = m0 + wrow + mi * 16 + quad * 4 + rr;  // token
                    int j = n0 + wcol + ni * 16 + lr;                // [0,2048)
                    float val = acc[mi][ni][rr];
                    int which = j >> 10, rem = j & 1023;
                    int nh = rem >> 6, hd = rem & 63;
                    int b = mrow >> 11, s = mrow & 2047;
                    size_t dst = ((size_t)(b * NHEAD + nh) * SEQ + s) * 64 + hd;
                    if (which == 0) q_out[dst] = f2bf(val * QSCALE);
                    else            k_out[dst] = f2bf(val);
                }
    } else {
#pragma unroll
        for (int mi = 0; mi < 4; mi++)
#pragma unroll
            for (int ni = 0; ni < 4; ni++)
#pragma unroll
                for (int rr = 0; rr < 4; rr++) {
                    int n = n0 + wcol + ni * 16 + quad * 4 + rr;     // channel
                    int m = m0 + wrow + mi * 16 + lr;                // token
                    float val = acc[mi][ni][rr];
                    int rem = n & 1023;
                    int nh = rem >> 6, hd = rem & 63;
                    int b = m >> 11, s = m & 2047;
                    size_t dst = ((size_t)(b * NHEAD + nh) * 64 + hd) * SEQ + s;  // V^T f16
                    v_out[dst] = f2h(val);
                }
    }
}

// --------------------------- MFMA GEMM 1: out = ao @ w_out^T ---------------
// R23: double-buffered BK=32 pipeline (same mechanism as gemm_qkv R22):
// per phase: barrier -> STAGE(next buf) -> setprio MFMA(cur buf).
__global__ __launch_bounds__(256) void gemm_out(
    const unsigned short* __restrict__ X, const unsigned short* __restrict__ Wc,
    const unsigned short* __restrict__ Wraw,
    void* __restrict__ d_out, const unsigned short* __restrict__ hs_raw) {
    const int K = 1024, N = 1024;
    __shared__ __align__(16) unsigned short Xs0[64 * 32];
    __shared__ __align__(16) unsigned short Xs1[64 * 32];
    __shared__ __align__(16) unsigned short Ws0[128 * 32];
    __shared__ __align__(16) unsigned short Ws1[128 * 32];

    const int isf32 = detect_f32(hs_raw);
    const unsigned short* W = isf32 ? Wc : Wraw;

    const int t = threadIdx.x;
    const int w = t >> 6, lane = t & 63, quad = lane >> 4, lr = lane & 15;
    const int wrow = (w >> 1) * 32, wcol = (w & 1) * 64;
    const int m0 = blockIdx.y * 64, n0 = blockIdx.x * 128;

    f32x4 acc[2][4];
#pragma unroll
    for (int mi = 0; mi < 2; mi++)
#pragma unroll
        for (int ni = 0; ni < 4; ni++) acc[mi][ni] = (f32x4){0.f, 0.f, 0.f, 0.f};

    const int sxrow = w * 16 + (lane >> 2);
    const int swrow = w * 32 + (lane >> 2);
    const int scol = (lane & 3) * 8;
    const unsigned short* xg = X + (size_t)(m0 + sxrow) * K + scol;
    const unsigned short* wg = W + (size_t)(n0 + swrow) * K + scol;
    unsigned short* xl0 = &Xs0[w * 512];
    unsigned short* xl1 = &Xs1[w * 512];
    unsigned short* wl0 = &Ws0[w * 1024];
    unsigned short* wl1 = &Ws1[w * 1024];

    // prologue: stage k=0 into buffer 0
    async16(xg, xl0);
    async16(wg, wl0);
    async16(wg + 16 * K, wl0 + 512);

#define OUT_COMPUTE(Xh, Wh)                                                            \
    {                                                                                  \
        bf16x8 af[2], bfr[4];                                                          \
        _Pragma("unroll")                                                              \
        for (int mi = 0; mi < 2; mi++)                                                 \
            af[mi] = *(const bf16x8*)&Xh[(wrow + mi * 16 + lr) * 32 + quad * 8];       \
        _Pragma("unroll")                                                              \
        for (int ni = 0; ni < 4; ni++)                                                 \
            bfr[ni] = *(const bf16x8*)&Wh[(wcol + ni * 16 + lr) * 32 + quad * 8];      \
        __builtin_amdgcn_s_setprio(1);                                                 \
        _Pragma("unroll")                                                              \
        for (int mi = 0; mi < 2; mi++)                                                 \
            _Pragma("unroll")                                                          \
            for (int ni = 0; ni < 4; ni++)                                             \
                acc[mi][ni] = __builtin_amdgcn_mfma_f32_16x16x32_bf16(                 \
                    af[mi], bfr[ni], acc[mi][ni], 0, 0, 0);                            \
        __builtin_amdgcn_s_setprio(0);                                                 \
    }

    for (int k0 = 0; k0 < K; k0 += 64) {
        __syncthreads();
        async16(xg + k0 + 32, xl1);
        async16(wg + k0 + 32, wl1);
        async16(wg + k0 + 32 + 16 * K, wl1 + 512);
        OUT_COMPUTE(Xs0, Ws0);

        __syncthreads();
        if (k0 + 64 < K) {
            async16(xg + k0 + 64, xl0);
            async16(wg + k0 + 64, wl0);
            async16(wg + k0 + 64 + 16 * K, wl0 + 512);
        }
        OUT_COMPUTE(Xs1, Ws1);
    }
#undef OUT_COMPUTE

#pragma unroll
    for (int mi = 0; mi < 2; mi++)
#pragma unroll
        for (int ni = 0; ni < 4; ni++)
#pragma unroll
            for (int rr = 0; rr < 4; rr++) {
                int mrow = m0 + wrow + mi * 16 + quad * 4 + rr;
                int j = n0 + wcol + ni * 16 + lr;
                float val = acc[mi][ni][rr];
                size_t dst = (size_t)mrow * N + j;
                if (isf32) ((float*)d_out)[dst] = val;
                else ((unsigned short*)d_out)[dst] = f2bf(val);
            }
}

// --------------------------- MFMA flash attention v12 ----------------------
// v7 structure + T5, KVBLK=128, twin V buffers, launch_bounds(256,2),
// mask folded into QK accumulator init. BYTE-IDENTICAL to R18-R20
// (measured 54.6us, MfmaUtil ~36).
// grid (B*NH, S/128), block 256 = 4 waves, 32 q-rows/wave.
// K [B,NH,S,HD] bf16; V^T [B,NH,HD,S] f16. q pre-scaled QSCALE.
__global__ __launch_bounds__(256, 2) void flash_attn_v12(
    const unsigned short* __restrict__ q, const unsigned short* __restrict__ k,
    const unsigned short* __restrict__ vt, const int* __restrict__ mask,
    unsigned short* __restrict__ attn_out) {
    __shared__ __align__(16) unsigned short Ks[128 * LSTRIDE];   // bf16, kk rows
    __shared__ __align__(16) unsigned short Vt0[64 * LSTRIDE];   // f16, d rows, kk 0-63
    __shared__ __align__(16) unsigned short Vt1[64 * LSTRIDE];   // f16, d rows, kk 64-127
    __shared__ __align__(16) float Msk[136];

    const int t = threadIdx.x;
    const int w = t >> 6, lane = t & 63, quad = lane >> 4, lr = lane & 15;
    const int bh = blockIdx.x, b = bh >> 4, h = bh & 15;
    const int q0 = blockIdx.y * 128;

    const unsigned short* qb = q + (size_t)bh * SEQ * 64;
    const unsigned short* kb = k + (size_t)bh * SEQ * 64;
    const unsigned short* vtb = vt + (size_t)bh * 64 * SEQ;
    const int* mb = mask + b * SEQ;

    // Q B-frags (x32 layout: B[n=lr][k=quad*8+j]), 2 q-groups x 2 hd-halves
    bf16x8 qf[2][2];
#pragma unroll
    for (int qg = 0; qg < 2; qg++) {
        const unsigned short* qrow = qb + (size_t)(q0 + w * 32 + qg * 16 + lr) * 64 + quad * 8;
        qf[qg][0] = *(const bf16x8*)qrow;
        qf[qg][1] = *(const bf16x8*)(qrow + 32);
    }

    f32x4 oacc[2][4];   // [qg][dt], O^T C-layout (d=dt*16+quad*4+rr, q=lr)
#pragma unroll
    for (int qg = 0; qg < 2; qg++)
#pragma unroll
        for (int dt = 0; dt < 4; dt++) oacc[qg][dt] = (f32x4){0.f, 0.f, 0.f, 0.f};
    float l_st[2] = {0.f, 0.f};

    const int sr = t >> 2;          // staging row 0..63
    const int sc = (t & 3) * 16;    // staging col group

    for (int kk0 = 0; kk0 < SEQ; kk0 += 128) {
        const uint4* kp0 = (const uint4*)(kb + (size_t)(kk0 + sr) * 64 + sc);
        const uint4* kp1 = (const uint4*)(kb + (size_t)(kk0 + 64 + sr) * 64 + sc);
        const uint4* vp0 = (const uint4*)(vtb + (size_t)sr * SEQ + kk0 + sc);
        const uint4* vp1 = (const uint4*)(vtb + (size_t)sr * SEQ + kk0 + 64 + sc);
        uint4 k0a = kp0[0], k0b = kp0[1];
        uint4 k1a = kp1[0], k1b = kp1[1];
        uint4 v0a = vp0[0], v0b = vp0[1];
        uint4 v1a = vp1[0], v1b = vp1[1];
        float mval = 0.f;
        if (t < 128) mval = (mb[kk0 + t] == 0) ? -1e30f : -F2SHIFT;

        __syncthreads();
        *(uint4*)&Ks[sr * LSTRIDE + sc] = k0a;
        *(uint4*)&Ks[sr * LSTRIDE + sc + 8] = k0b;
        *(uint4*)&Ks[(64 + sr) * LSTRIDE + sc] = k1a;
        *(uint4*)&Ks[(64 + sr) * LSTRIDE + sc + 8] = k1b;
        *(uint4*)&Vt0[sr * LSTRIDE + sc] = v0a;
        *(uint4*)&Vt0[sr * LSTRIDE + sc + 8] = v0b;
        *(uint4*)&Vt1[sr * LSTRIDE + sc] = v1a;
        *(uint4*)&Vt1[sr * LSTRIDE + sc + 8] = v1b;
        if (t < 128) Msk[t] = mval;
        __syncthreads();

        __builtin_amdgcn_s_setprio(1);
#pragma unroll
        for (int mt = 0; mt < 8; mt++) {
            bf16x8 a1h0 = *(bf16x8*)&Ks[(mt * 16 + lr) * LSTRIDE + quad * 8];
            bf16x8 a1h1 = *(bf16x8*)&Ks[(mt * 16 + lr) * LSTRIDE + 32 + quad * 8];
            const unsigned short* vb_ = (mt < 4) ? Vt0 : Vt1;
            const int mcol = (mt & 3) * 16;
            f16x4 a2[4];
#pragma unroll
            for (int dt = 0; dt < 4; dt++)
                a2[dt] = *(const f16x4*)&vb_[(dt * 16 + lr) * LSTRIDE + mcol + quad * 4];
            float4 mv = *(const float4*)&Msk[mt * 16 + quad * 4];
            // mask folded into the QK accumulator init (read-only input to
            // the first MFMA of each q-group; proven R13-R15)
            f32x4 zi = (f32x4){mv.x, mv.y, mv.z, mv.w};

#pragma unroll
            for (int qg = 0; qg < 2; qg++) {
                f32x4 z = __builtin_amdgcn_mfma_f32_16x16x32_bf16(a1h0, qf[qg][0], zi, 0, 0, 0);
                z = __builtin_amdgcn_mfma_f32_16x16x32_bf16(a1h1, qf[qg][1], z, 0, 0, 0);
                float p0 = __builtin_amdgcn_exp2f(z[0]);
                float p1 = __builtin_amdgcn_exp2f(z[1]);
                float p2 = __builtin_amdgcn_exp2f(z[2]);
                float p3 = __builtin_amdgcn_exp2f(z[3]);
                l_st[qg] += (p0 + p1) + (p2 + p3);
                f16x2 ab = pkrtz(p0, p1);
                f16x2 cd = pkrtz(p2, p3);
                f16x4 b2;
                b2[0] = ab[0]; b2[1] = ab[1]; b2[2] = cd[0]; b2[3] = cd[1];
#pragma unroll
                for (int dt = 0; dt < 4; dt++)
                    oacc[qg][dt] = __builtin_amdgcn_mfma_f32_16x16x16f16(a2[dt], b2, oacc[qg][dt], 0, 0, 0);
            }
        }
        __builtin_amdgcn_s_setprio(0);
    }

    // l: sum over quads (each quad held a disjoint kk subset)
    float inv[2];
#pragma unroll
    for (int qg = 0; qg < 2; qg++) {
        float s = l_st[qg];
        s += __shfl_xor(s, 16);
        s += __shfl_xor(s, 32);
        inv[qg] = 1.0f / s;
    }
    // O^T C-layout: lane (quad,lr) holds (d=dt*16+quad*4+rr, q=lr)
#pragma unroll
    for (int qg = 0; qg < 2; qg++) {
        size_t tok = (size_t)(b * SEQ + q0 + w * 32 + qg * 16 + lr);
#pragma unroll
        for (int dt = 0; dt < 4; dt++)
#pragma unroll
            for (int rr = 0; rr < 4; rr++)
                attn_out[tok * HDIM + h * 64 + dt * 16 + quad * 4 + rr] =
                    f2bf(oacc[qg][dt][rr] * inv[qg]);
    }
}

// ---------------------------------------------------------------------------
extern "C" void kernel_launch(void* const* d_in, const int* in_sizes, int n_in,
                              void* d_out, int out_size, void* d_ws, size_t ws_size,
                              hipStream_t stream) {
    const void* hs_raw = d_in[0];
    const int* mask = (const int*)d_in[1];
    const void* wqkv_raw = d_in[2];
    const void* wout_raw = d_in[3];

    char* wsb = (char*)d_ws;
    unsigned short* hs_c = (unsigned short*)(wsb + 256);
    unsigned short* wqkv_c = hs_c + 4194304;     // 2*2048*1024
    unsigned short* wout_c = wqkv_c + 3145728;   // 3072*1024
    unsigned short* qw = wout_c + 1048576;       // 1024*1024
    unsigned short* kw = qw + 4194304;
    unsigned short* vtw = kw + 4194304;          // V^T [B,NH,HD,S] f16
    unsigned short* ao = vtw + 4194304;          // attn_out [4096,1024] bf16

    convert3_kernel<<<1024, 256, 0, stream>>>(hs_raw, wqkv_raw, wout_raw, hs_c);

    gemm_qkv<<<768, 256, 0, stream>>>(hs_c, wqkv_c,
                                      (const unsigned short*)hs_raw,
                                      (const unsigned short*)wqkv_raw,
                                      qw, kw, vtw);
    flash_attn_v12<<<dim3(32, 16), 256, 0, stream>>>(qw, kw, vtw, mask, ao);
    gemm_out<<<dim3(8, 64), 256, 0, stream>>>(ao, wout_c,
                                              (const unsigned short*)wout_raw, d_out,
                                              (const unsigned short*)hs_raw);
}